// Round 19
// baseline (152.313 us; speedup 1.0000x reference)
//
#include <hip/hip_runtime.h>
#include <stdint.h>

#define B_ 8
#define N_ 4096
#define D_ 512
#define INV_T 0.04419417382415922f  // 1/sqrt(512)

typedef unsigned short u16;
typedef float f32x2 __attribute__((ext_vector_type(2)));
typedef float f32x4 __attribute__((ext_vector_type(4)));
typedef __bf16 bf16x8 __attribute__((ext_vector_type(8)));
typedef unsigned short u16x8 __attribute__((ext_vector_type(8)));

__device__ __forceinline__ u16 f2bf(float x) {
  union { float f; uint32_t u; } c;
  c.f = x;
  uint32_t r = c.u + 0x7FFFu + ((c.u >> 16) & 1u);
  return (u16)(r >> 16);
}

__device__ __forceinline__ void load_lds16(const u16* g, u16* l) {
  __builtin_amdgcn_global_load_lds(
      (__attribute__((address_space(1))) void*)(g),
      (__attribute__((address_space(3))) void*)(l), 16, 0, 0);
}

__device__ __forceinline__ void barrier_lgkm_only() {
  asm volatile("s_waitcnt lgkmcnt(0)" ::: "memory");
  __builtin_amdgcn_sched_barrier(0);
  __builtin_amdgcn_s_barrier();
  __builtin_amdgcn_sched_barrier(0);
}

// ---------- ABLATION PROBES (no global writes; keepalive per rule #17) ----

// A1: gemm1c's load stream ONLY (f32x2 x16/step), same grid/addressing.
__global__ __launch_bounds__(512) void k_ab_load(const float* __restrict__ kin,
                                                 const float* __restrict__ vin) {
  const int flat = blockIdx.x;
  const int swz = (flat & 7) * 32 + (flat >> 3);
  const int z = swz >> 2;
  const int tile = swz & 3;
  const int b = z & 7, kz = z >> 3;
  const int bm = tile >> 1, bn = tile & 1;
  const int tid = threadIdx.x;
  const int dp = tid & 127, oct = tid >> 7;
  const float* ga = kin + (size_t)b * N_ * D_ +
                    (size_t)(kz * 512 + oct * 8) * D_ + bm * 256 + 2 * dp;
  const float* gb = vin + (size_t)b * N_ * D_ +
                    (size_t)(kz * 512 + oct * 8) * D_ + bn * 256 + 2 * dp;
  float s0 = 0.f, s1 = 0.f;
  for (int kt = 0; kt < 16; ++kt) {
    f32x2 rA[8], rB[8];
#pragma unroll
    for (int j = 0; j < 8; ++j) {
      rA[j] = *(const f32x2*)(ga + (size_t)(kt * 32 + j) * D_);
      rB[j] = *(const f32x2*)(gb + (size_t)(kt * 32 + j) * D_);
    }
#pragma unroll
    for (int j = 0; j < 8; ++j) {
      s0 += rA[j][0] + rA[j][1];
      s1 += rB[j][0] + rB[j][1];
    }
    asm volatile("" ::"v"(s0), "v"(s1));  // keep loads live, pin per-iter order
  }
}

// A2: same bytes via f32x4 (half the load instructions).
__global__ __launch_bounds__(512) void k_ab_load4(const float* __restrict__ kin,
                                                  const float* __restrict__ vin) {
  const int flat = blockIdx.x;
  const int swz = (flat & 7) * 32 + (flat >> 3);
  const int z = swz >> 2;
  const int tile = swz & 3;
  const int b = z & 7, kz = z >> 3;
  const int bm = tile >> 1, bn = tile & 1;
  const int tid = threadIdx.x;
  const int dp4 = tid & 63, oct4 = tid >> 6;  // 8 groups x 4 rows
  const float* ga = kin + (size_t)b * N_ * D_ +
                    (size_t)(kz * 512 + oct4 * 4) * D_ + bm * 256 + 4 * dp4;
  const float* gb = vin + (size_t)b * N_ * D_ +
                    (size_t)(kz * 512 + oct4 * 4) * D_ + bn * 256 + 4 * dp4;
  float s0 = 0.f, s1 = 0.f;
  for (int kt = 0; kt < 16; ++kt) {
    f32x4 rA[4], rB[4];
#pragma unroll
    for (int j = 0; j < 4; ++j) {
      rA[j] = *(const f32x4*)(ga + (size_t)(kt * 32 + j) * D_);
      rB[j] = *(const f32x4*)(gb + (size_t)(kt * 32 + j) * D_);
    }
#pragma unroll
    for (int j = 0; j < 4; ++j) {
      s0 += rA[j][0] + rA[j][1] + rA[j][2] + rA[j][3];
      s1 += rB[j][0] + rB[j][1] + rB[j][2] + rB[j][3];
    }
    asm volatile("" ::"v"(s0), "v"(s1));
  }
}

// A3: full gemm1c minus MFMA and C-write (loads + cvt + LDS writes + barrier
// + fragment reads, all kept live).
__global__ __launch_bounds__(512) void k_ab_nomfma(const float* __restrict__ kin,
                                                   const float* __restrict__ vin) {
  __shared__ u16 As[2][256 * 32];
  __shared__ u16 Bs[2][256 * 32];
  const int flat = blockIdx.x;
  const int swz = (flat & 7) * 32 + (flat >> 3);
  const int z = swz >> 2;
  const int tile = swz & 3;
  const int b = z & 7, kz = z >> 3;
  const int bm = tile >> 1, bn = tile & 1;
  const int tid = threadIdx.x;
  const int wave = tid >> 6, lane = tid & 63;
  const int wrow = wave >> 1, wcol = wave & 1;
  const int lrow = lane & 15, lk = lane >> 4;
  const int dp = tid & 127, oct = tid >> 7;
  const float* ga = kin + (size_t)b * N_ * D_ +
                    (size_t)(kz * 512 + oct * 8) * D_ + bm * 256 + 2 * dp;
  const float* gb = vin + (size_t)b * N_ * D_ +
                    (size_t)(kz * 512 + oct * 8) * D_ + bn * 256 + 2 * dp;
  const int wslot = 8 * (oct ^ (dp & 3));
  f32x2 rA[8], rB[8];
#pragma unroll
  for (int j = 0; j < 8; ++j) {
    rA[j] = *(const f32x2*)(ga + (size_t)j * D_);
    rB[j] = *(const f32x2*)(gb + (size_t)j * D_);
  }
  for (int kt = 0; kt < 16; ++kt) {
    {
      bf16x8 a0, a1, b0, b1;
#pragma unroll
      for (int j = 0; j < 8; ++j) {
        a0[j] = (__bf16)rA[j][0];
        a1[j] = (__bf16)rA[j][1];
        b0[j] = (__bf16)rB[j][0];
        b1[j] = (__bf16)rB[j][1];
      }
      *(bf16x8*)(As[kt & 1] + (2 * dp) * 32 + wslot) = a0;
      *(bf16x8*)(As[kt & 1] + (2 * dp + 1) * 32 + wslot) = a1;
      *(bf16x8*)(Bs[kt & 1] + (2 * dp) * 32 + wslot) = b0;
      *(bf16x8*)(Bs[kt & 1] + (2 * dp + 1) * 32 + wslot) = b1;
    }
    if (kt + 1 < 16) {
#pragma unroll
      for (int j = 0; j < 8; ++j) {
        rA[j] = *(const f32x2*)(ga + (size_t)((kt + 1) * 32 + j) * D_);
        rB[j] = *(const f32x2*)(gb + (size_t)((kt + 1) * 32 + j) * D_);
      }
    }
    barrier_lgkm_only();
    {
      bf16x8 af[4], bfv[8];
#pragma unroll
      for (int m = 0; m < 4; ++m) {
        const int row = wrow * 64 + m * 16 + lrow;
        af[m] = *(const bf16x8*)(As[kt & 1] + row * 32 +
                                 8 * (lk ^ ((row >> 1) & 3)));
      }
#pragma unroll
      for (int n = 0; n < 8; ++n) {
        const int row = wcol * 128 + n * 16 + lrow;
        bfv[n] = *(const bf16x8*)(Bs[kt & 1] + row * 32 +
                                  8 * (lk ^ ((row >> 1) & 3)));
      }
#pragma unroll
      for (int m = 0; m < 4; ++m) asm volatile("" ::"v"(*(f32x4*)&af[m]));
#pragma unroll
      for (int n = 0; n < 8; ++n) asm volatile("" ::"v"(*(f32x4*)&bfv[n]));
    }
  }
}

// ---------- REAL PIPELINE (r14-proven pieces + r18 gemm2 mapping) ---------

// Fused transpose+gemm1, 256x256 tile, split-K=8, 512 threads (r14-proven).
__global__ __launch_bounds__(512) void k_gemm1c(const float* __restrict__ kin,
                                                const float* __restrict__ vin,
                                                float* __restrict__ Sp) {
  __shared__ u16 As[2][256 * 32];
  __shared__ u16 Bs[2][256 * 32];
  const int flat = blockIdx.x;
  const int swz = (flat & 7) * 32 + (flat >> 3);
  const int z = swz >> 2;
  const int tile = swz & 3;
  const int b = z & 7, kz = z >> 3;
  const int bm = tile >> 1, bn = tile & 1;
  const int tid = threadIdx.x;
  const int wave = tid >> 6, lane = tid & 63;
  const int wrow = wave >> 1, wcol = wave & 1;
  const int lrow = lane & 15, lk = lane >> 4;
  const int dp = tid & 127, oct = tid >> 7;
  const float* ga = kin + (size_t)b * N_ * D_ +
                    (size_t)(kz * 512 + oct * 8) * D_ + bm * 256 + 2 * dp;
  const float* gb = vin + (size_t)b * N_ * D_ +
                    (size_t)(kz * 512 + oct * 8) * D_ + bn * 256 + 2 * dp;
  float* C = Sp + (size_t)z * ((size_t)D_ * D_);
  const int wslot = 8 * (oct ^ (dp & 3));

  f32x4 acc[4][8];
#pragma unroll
  for (int m = 0; m < 4; ++m)
#pragma unroll
    for (int n = 0; n < 8; ++n) acc[m][n] = f32x4{0.f, 0.f, 0.f, 0.f};

  f32x2 rA[8], rB[8];

#define LOADSET(STEP)                                                      \
  {                                                                        \
    _Pragma("unroll") for (int j = 0; j < 8; ++j) {                        \
      rA[j] = *(const f32x2*)(ga + (size_t)((STEP)*32 + j) * D_);          \
      rB[j] = *(const f32x2*)(gb + (size_t)((STEP)*32 + j) * D_);          \
    }                                                                      \
  }
#define CVTW(BUF)                                                          \
  {                                                                        \
    bf16x8 a0, a1, b0, b1;                                                 \
    _Pragma("unroll") for (int j = 0; j < 8; ++j) {                        \
      a0[j] = (__bf16)rA[j][0];                                            \
      a1[j] = (__bf16)rA[j][1];                                            \
      b0[j] = (__bf16)rB[j][0];                                            \
      b1[j] = (__bf16)rB[j][1];                                            \
    }                                                                      \
    *(bf16x8*)(As[BUF] + (2 * dp) * 32 + wslot) = a0;                      \
    *(bf16x8*)(As[BUF] + (2 * dp + 1) * 32 + wslot) = a1;                  \
    *(bf16x8*)(Bs[BUF] + (2 * dp) * 32 + wslot) = b0;                      \
    *(bf16x8*)(Bs[BUF] + (2 * dp + 1) * 32 + wslot) = b1;                  \
  }
#define FRAGS_MFMA(BUF)                                                    \
  {                                                                        \
    bf16x8 af[4], bfv[8];                                                  \
    _Pragma("unroll") for (int m = 0; m < 4; ++m) {                        \
      const int row = wrow * 64 + m * 16 + lrow;                           \
      af[m] = *(const bf16x8*)(As[BUF] + row * 32 +                        \
                               8 * (lk ^ ((row >> 1) & 3)));               \
    }                                                                      \
    _Pragma("unroll") for (int n = 0; n < 8; ++n) {                        \
      const int row = wcol * 128 + n * 16 + lrow;                          \
      bfv[n] = *(const bf16x8*)(Bs[BUF] + row * 32 +                       \
                                8 * (lk ^ ((row >> 1) & 3)));              \
    }                                                                      \
    _Pragma("unroll") for (int m = 0; m < 4; ++m)                          \
      _Pragma("unroll") for (int n = 0; n < 8; ++n)                        \
        acc[m][n] = __builtin_amdgcn_mfma_f32_16x16x32_bf16(               \
            af[m], bfv[n], acc[m][n], 0, 0, 0);                            \
  }

  LOADSET(0)
  for (int kt = 0; kt < 16; ++kt) {
    CVTW(kt & 1)
    if (kt + 1 < 16) LOADSET(kt + 1)
    barrier_lgkm_only();
    FRAGS_MFMA(kt & 1)
  }
#undef LOADSET
#undef CVTW
#undef FRAGS_MFMA

  const int crow = (lane >> 4) * 4, ccol = lane & 15;
#pragma unroll
  for (int m = 0; m < 4; ++m) {
    const int grow = bm * 256 + wrow * 64 + m * 16 + crow;
#pragma unroll
    for (int n = 0; n < 8; ++n) {
      const int gcol = bn * 256 + wcol * 128 + n * 16 + ccol;
#pragma unroll
      for (int i2 = 0; i2 < 4; ++i2)
        C[(size_t)(grow + i2) * D_ + gcol] = acc[m][n][i2];
    }
  }
}

// Sum 8 split-K partials, scale by 1/T, softmax rows, write attn fp32 only
// (r14-proven; the fused attnT scatter was a measured regression in r18).
__global__ __launch_bounds__(256) void k_softmax(const float* __restrict__ Sp,
                                                 float* __restrict__ attn) {
  const int t = threadIdx.x;
  const int wave = t >> 6, lane = t & 63;
  const int g = blockIdx.x * 4 + wave;
  const int b = g >> 9, d = g & 511;
  const float* base = Sp + (size_t)b * (D_ * D_) + (size_t)d * D_ + lane * 8;
  float s[8];
#pragma unroll
  for (int jj = 0; jj < 8; ++jj) s[jj] = 0.f;
#pragma unroll
  for (int kz = 0; kz < 8; ++kz) {
    const f32x4 p0 = *(const f32x4*)(base + (size_t)kz * 8 * (D_ * D_));
    const f32x4 p1 = *(const f32x4*)(base + (size_t)kz * 8 * (D_ * D_) + 4);
#pragma unroll
    for (int jj = 0; jj < 4; ++jj) { s[jj] += p0[jj]; s[4 + jj] += p1[jj]; }
  }
#pragma unroll
  for (int jj = 0; jj < 8; ++jj) s[jj] *= INV_T;
  float mx = s[0];
#pragma unroll
  for (int jj = 1; jj < 8; ++jj) mx = fmaxf(mx, s[jj]);
  for (int o = 32; o > 0; o >>= 1) mx = fmaxf(mx, __shfl_xor(mx, o));
  float sum = 0.f;
#pragma unroll
  for (int jj = 0; jj < 8; ++jj) { s[jj] = __expf(s[jj] - mx); sum += s[jj]; }
  for (int o = 32; o > 0; o >>= 1) sum += __shfl_xor(sum, o);
  const float inv = 1.0f / sum;
  float* orow = attn + (size_t)b * (D_ * D_) + (size_t)d * D_ + lane * 8;
  f32x4 o0, o1;
#pragma unroll
  for (int jj = 0; jj < 4; ++jj) { o0[jj] = s[jj] * inv; o1[jj] = s[4 + jj] * inv; }
  *(f32x4*)orow = o0;
  *(f32x4*)(orow + 4) = o1;
}

// attn fp32 [b][d][e] -> attnT bf16 [b][e][d]  (r14-proven coalesced tile)
__global__ __launch_bounds__(256) void k_attn_t(const float* __restrict__ attn,
                                                u16* __restrict__ attnT) {
  __shared__ float lds[64][65];
  const int t = threadIdx.x;
  const int b = blockIdx.z;
  const float* src = attn + (size_t)b * D_ * D_;
  u16* dst = attnT + (size_t)b * D_ * D_;
  const int d0 = blockIdx.x * 64, e0 = blockIdx.y * 64;
#pragma unroll
  for (int i = 0; i < 4; ++i) {
    const int fidx = i * 256 + t;
    const int r = fidx >> 4, c4 = fidx & 15;
    const f32x4 f = *(const f32x4*)(src + (size_t)(d0 + r) * D_ + e0 + c4 * 4);
#pragma unroll
    for (int jj = 0; jj < 4; ++jj) lds[r][c4 * 4 + jj] = f[jj];
  }
  __syncthreads();
#pragma unroll
  for (int j = 0; j < 2; ++j) {
    const int sidx = j * 256 + t;
    const int rd = sidx >> 3, c8 = sidx & 7;
    u16x8 o;
#pragma unroll
    for (int jj = 0; jj < 8; ++jj) o[jj] = f2bf(lds[c8 * 8 + jj][rd]);
    *(u16x8*)(dst + (size_t)(e0 + rd) * D_ + d0 + c8 * 8) = o;
  }
}

// gemm2: out[b][n][e] = sum_d v[b][n][d] * attnT[b][e][d]
// r6-proven double-buffer; batch->XCD 1D mapping (r18).
__global__ __launch_bounds__(256) void k_gemm2(const float* __restrict__ v,
                                               const u16* __restrict__ attnT,
                                               float* __restrict__ out) {
  __shared__ u16 As2[2][128 * 32];
  __shared__ u16 Bs2[2][128 * 32];
  const int flat = blockIdx.x;
  const int b = flat & 7;
  const int j = flat >> 3;
  const int bm = j & 31, bn = j >> 5;
  const float* Ab = v + (size_t)b * ((size_t)N_ * D_) + (size_t)(bm * 128) * D_;
  const u16* Bb = attnT + (size_t)b * ((size_t)D_ * D_) + (size_t)(bn * 128) * D_;
  float* C = out + (size_t)b * ((size_t)N_ * D_);
  const int tid = threadIdx.x;
  const int wave = tid >> 6, lane = tid & 63;
  const int wr = wave >> 1, wc = wave & 1;
  const int lrow = lane & 15, lk = (lane >> 4) * 8;
  const int srow = lane >> 2, scol = (lane & 3) * 8;
  const int arow0 = tid >> 2, ac8 = tid & 3;
  f32x4 acc[4][4];
#pragma unroll
  for (int m = 0; m < 4; ++m)
#pragma unroll
    for (int n = 0; n < 4; ++n) acc[m][n] = f32x4{0.f, 0.f, 0.f, 0.f};

  f32x4 rf0[2], rf1[2];
#pragma unroll
  for (int i = 0; i < 2; ++i) {
    const int row = i * 64 + arow0;
    rf0[i] = *(const f32x4*)(Ab + (size_t)row * D_ + ac8 * 8);
    rf1[i] = *(const f32x4*)(Ab + (size_t)row * D_ + ac8 * 8 + 4);
  }

  for (int kt = 0; kt < 16; ++kt) {
    const int k0 = kt * 32;
    u16* Ad = As2[kt & 1];
    u16* Bd = Bs2[kt & 1];
#pragma unroll
    for (int i = 0; i < 2; ++i) {
      const int cc = i * 4 + wave;
      load_lds16(Bb + (size_t)(cc * 16 + srow) * D_ + k0 + scol, Bd + cc * 512);
    }
#pragma unroll
    for (int i = 0; i < 2; ++i) {
      const int row = i * 64 + arow0;
      bf16x8 o;
#pragma unroll
      for (int jj = 0; jj < 4; ++jj) {
        o[jj] = (__bf16)rf0[i][jj];
        o[4 + jj] = (__bf16)rf1[i][jj];
      }
      *(bf16x8*)(Ad + row * 32 + ac8 * 8) = o;
    }
    if (kt + 1 < 16) {
#pragma unroll
      for (int i = 0; i < 2; ++i) {
        const int row = i * 64 + arow0;
        rf0[i] = *(const f32x4*)(Ab + (size_t)row * D_ + (k0 + 32) + ac8 * 8);
        rf1[i] = *(const f32x4*)(Ab + (size_t)row * D_ + (k0 + 32) + ac8 * 8 + 4);
      }
    }
    __syncthreads();
    bf16x8 af[4], bfv[4];
#pragma unroll
    for (int m = 0; m < 4; ++m)
      af[m] = *(const bf16x8*)(Ad + (wr * 64 + m * 16 + lrow) * 32 + lk);
#pragma unroll
    for (int n = 0; n < 4; ++n)
      bfv[n] = *(const bf16x8*)(Bd + (wc * 64 + n * 16 + lrow) * 32 + lk);
#pragma unroll
    for (int m = 0; m < 4; ++m)
#pragma unroll
      for (int n = 0; n < 4; ++n)
        acc[m][n] = __builtin_amdgcn_mfma_f32_16x16x32_bf16(af[m], bfv[n],
                                                            acc[m][n], 0, 0, 0);
  }
  const int crow = (lane >> 4) * 4, ccol = lane & 15;
#pragma unroll
  for (int m = 0; m < 4; ++m) {
    const int grow = bm * 128 + wr * 64 + m * 16 + crow;
#pragma unroll
    for (int n = 0; n < 4; ++n) {
      const int gcol = bn * 128 + wc * 64 + n * 16 + ccol;
#pragma unroll
      for (int i2 = 0; i2 < 4; ++i2)
        C[(size_t)(grow + i2) * D_ + gcol] = acc[m][n][i2];
    }
  }
}

extern "C" void kernel_launch(void* const* d_in, const int* in_sizes, int n_in,
                              void* d_out, int out_size, void* d_ws, size_t ws_size,
                              hipStream_t stream) {
  const float* v = (const float*)d_in[0];
  const float* k = (const float*)d_in[1];
  float* out = (float*)d_out;
  float* attn = out + (size_t)B_ * N_ * D_;
  float* Sp = (float*)d_out;     // 8 x [8][512][512] f32 = 64 MiB (dead until gemm2)
  u16* attnT = (u16*)d_ws;       // 4 MiB

  // --- ablation probes (no writes; diagnosis via rocprof per-dispatch dur) ---
  k_ab_load<<<dim3(256), dim3(512), 0, stream>>>(k, v);
  k_ab_load4<<<dim3(256), dim3(512), 0, stream>>>(k, v);
  k_ab_nomfma<<<dim3(256), dim3(512), 0, stream>>>(k, v);
  // --- real pipeline ---
  k_gemm1c<<<dim3(256), dim3(512), 0, stream>>>(k, v, Sp);
  k_softmax<<<dim3(1024), dim3(256), 0, stream>>>(Sp, attn);
  k_attn_t<<<dim3(8, 8, 8), dim3(256), 0, stream>>>(attn, attnT);
  k_gemm2<<<dim3(1024), dim3(256), 0, stream>>>(v, attnT, out);
}

// Round 20
// 88.637 us; speedup vs baseline: 1.7184x; 1.7184x over previous
//
#include <hip/hip_runtime.h>
#include <stdint.h>

#define B_ 8
#define N_ 4096
#define D_ 512
#define INV_T 0.04419417382415922f  // 1/sqrt(512)

typedef unsigned short u16;
typedef float f32x4 __attribute__((ext_vector_type(4)));
typedef __bf16 bf16x8 __attribute__((ext_vector_type(8)));
typedef unsigned short u16x8 __attribute__((ext_vector_type(8)));

__device__ __forceinline__ u16 f2bf(float x) {
  union { float f; uint32_t u; } c;
  c.f = x;
  uint32_t r = c.u + 0x7FFFu + ((c.u >> 16) & 1u);
  return (u16)(r >> 16);
}

__device__ __forceinline__ void load_lds16(const u16* g, u16* l) {
  __builtin_amdgcn_global_load_lds(
      (__attribute__((address_space(1))) void*)(g),
      (__attribute__((address_space(3))) void*)(l), 16, 0, 0);
}

__device__ __forceinline__ void barrier_lgkm_only() {
  asm volatile("s_waitcnt lgkmcnt(0)" ::: "memory");
  __builtin_amdgcn_sched_barrier(0);
  __builtin_amdgcn_s_barrier();
  __builtin_amdgcn_s_barrier();  // (no-op dup guard removed below)
}

// NOTE: single-barrier version used in kernels (the duplicate above is never
// called; kept code path identical to r14 via barrier1 below).
__device__ __forceinline__ void barrier1() {
  asm volatile("s_waitcnt lgkmcnt(0)" ::: "memory");
  __builtin_amdgcn_sched_barrier(0);
  __builtin_amdgcn_s_barrier();
  __builtin_amdgcn_sched_barrier(0);
}

// Fused transpose+gemm1, 256x256 tile, split-K=8, 512 threads.
// v2: f32x4 loads (HALF the load instructions of r14, same bytes, identical
// LDS layout/swizzle). Threads split: t<256 stage A(k), t>=256 stage B(v);
// each thread owns a 4d x 8n cell: 8 f32x4 loads -> 4 bf16x8 LDS writes.
__global__ __launch_bounds__(512) void k_gemm1d(const float* __restrict__ kin,
                                                const float* __restrict__ vin,
                                                float* __restrict__ Sp) {
  __shared__ u16 As[2][256 * 32];  // [d][32n] bf16, slot-swizzled (r14 map)
  __shared__ u16 Bs[2][256 * 32];
  const int flat = blockIdx.x;  // 0..255, XCD-swizzled
  const int swz = (flat & 7) * 32 + (flat >> 3);
  const int z = swz >> 2;                      // 0..63
  const int tile = swz & 3;
  const int b = z & 7, kz = z >> 3;            // split-K = 8
  const int bm = tile >> 1, bn = tile & 1;
  const int tid = threadIdx.x;
  const int wave = tid >> 6, lane = tid & 63;
  const int wrow = wave >> 1, wcol = wave & 1;  // wave tile 64x128
  const int lrow = lane & 15, lk = lane >> 4;
  const int c = tid & 255, isB = tid >> 8;      // staging role
  const int dq = c & 63, og = c >> 6;           // d-quad, n-oct
  const float* gp = (isB ? vin : kin) + (size_t)b * N_ * D_ +
                    (size_t)(kz * 512 + og * 8) * D_ +
                    (isB ? bn : bm) * 256 + 4 * dq;
  float* C = Sp + (size_t)z * ((size_t)D_ * D_);

  f32x4 acc[4][8];
#pragma unroll
  for (int m = 0; m < 4; ++m)
#pragma unroll
    for (int n = 0; n < 8; ++n) acc[m][n] = f32x4{0.f, 0.f, 0.f, 0.f};

  f32x4 r[8];

#define LOADSET(STEP)                                                      \
  {                                                                        \
    _Pragma("unroll") for (int j = 0; j < 8; ++j) r[j] =                   \
        *(const f32x4*)(gp + (size_t)((STEP)*32 + j) * D_);                \
  }
#define CVTW(BUF)                                                          \
  {                                                                        \
    u16* dst = isB ? Bs[BUF] : As[BUF];                                    \
    _Pragma("unroll") for (int i = 0; i < 4; ++i) {                        \
      bf16x8 w;                                                            \
      _Pragma("unroll") for (int j = 0; j < 8; ++j) w[j] = (__bf16)r[j][i];\
      const int row = 4 * dq + i;                                          \
      *(bf16x8*)(dst + row * 32 + 8 * (og ^ ((row >> 1) & 3))) = w;        \
    }                                                                      \
  }
#define FRAGS_MFMA(BUF)                                                    \
  {                                                                        \
    bf16x8 af[4], bfv[8];                                                  \
    _Pragma("unroll") for (int m = 0; m < 4; ++m) {                        \
      const int row = wrow * 64 + m * 16 + lrow;                           \
      af[m] = *(const bf16x8*)(As[BUF] + row * 32 +                        \
                               8 * (lk ^ ((row >> 1) & 3)));               \
    }                                                                      \
    _Pragma("unroll") for (int n = 0; n < 8; ++n) {                        \
      const int row = wcol * 128 + n * 16 + lrow;                          \
      bfv[n] = *(const bf16x8*)(Bs[BUF] + row * 32 +                       \
                                8 * (lk ^ ((row >> 1) & 3)));              \
    }                                                                      \
    _Pragma("unroll") for (int m = 0; m < 4; ++m)                          \
      _Pragma("unroll") for (int n = 0; n < 8; ++n)                        \
        acc[m][n] = __builtin_amdgcn_mfma_f32_16x16x32_bf16(               \
            af[m], bfv[n], acc[m][n], 0, 0, 0);                            \
  }

  LOADSET(0)
  for (int kt = 0; kt < 16; ++kt) {
    CVTW(kt & 1)
    if (kt + 1 < 16) LOADSET(kt + 1)
    barrier1();  // lgkm-only: prefetch loads stay in flight across barrier
    FRAGS_MFMA(kt & 1)
  }
#undef LOADSET
#undef CVTW
#undef FRAGS_MFMA

  // C/D layout (m89-verified): row = (lane>>4)*4 + reg, col = lane&15
  const int crow = (lane >> 4) * 4, ccol = lane & 15;
#pragma unroll
  for (int m = 0; m < 4; ++m) {
    const int grow = bm * 256 + wrow * 64 + m * 16 + crow;
#pragma unroll
    for (int n = 0; n < 8; ++n) {
      const int gcol = bn * 256 + wcol * 128 + n * 16 + ccol;
#pragma unroll
      for (int i2 = 0; i2 < 4; ++i2)
        C[(size_t)(grow + i2) * D_ + gcol] = acc[m][n][i2];
    }
  }
}

// Sum 8 split-K partials, scale by 1/T, softmax rows, write attn fp32 (r14).
__global__ __launch_bounds__(256) void k_softmax(const float* __restrict__ Sp,
                                                 float* __restrict__ attn) {
  const int t = threadIdx.x;
  const int wave = t >> 6, lane = t & 63;
  const int g = blockIdx.x * 4 + wave;
  const int b = g >> 9, d = g & 511;
  const float* base = Sp + (size_t)b * (D_ * D_) + (size_t)d * D_ + lane * 8;
  float s[8];
#pragma unroll
  for (int jj = 0; jj < 8; ++jj) s[jj] = 0.f;
#pragma unroll
  for (int kz = 0; kz < 8; ++kz) {
    const f32x4 p0 = *(const f32x4*)(base + (size_t)kz * 8 * (D_ * D_));
    const f32x4 p1 = *(const f32x4*)(base + (size_t)kz * 8 * (D_ * D_) + 4);
#pragma unroll
    for (int jj = 0; jj < 4; ++jj) { s[jj] += p0[jj]; s[4 + jj] += p1[jj]; }
  }
#pragma unroll
  for (int jj = 0; jj < 8; ++jj) s[jj] *= INV_T;
  float mx = s[0];
#pragma unroll
  for (int jj = 1; jj < 8; ++jj) mx = fmaxf(mx, s[jj]);
  for (int o = 32; o > 0; o >>= 1) mx = fmaxf(mx, __shfl_xor(mx, o));
  float sum = 0.f;
#pragma unroll
  for (int jj = 0; jj < 8; ++jj) { s[jj] = __expf(s[jj] - mx); sum += s[jj]; }
  for (int o = 32; o > 0; o >>= 1) sum += __shfl_xor(sum, o);
  const float inv = 1.0f / sum;
  float* orow = attn + (size_t)b * (D_ * D_) + (size_t)d * D_ + lane * 8;
  f32x4 o0, o1;
#pragma unroll
  for (int jj = 0; jj < 4; ++jj) { o0[jj] = s[jj] * inv; o1[jj] = s[4 + jj] * inv; }
  *(f32x4*)orow = o0;
  *(f32x4*)(orow + 4) = o1;
}

// attn fp32 [b][d][e] -> attnT bf16 [b][e][d]  (r14-proven coalesced tile)
__global__ __launch_bounds__(256) void k_attn_t(const float* __restrict__ attn,
                                                u16* __restrict__ attnT) {
  __shared__ float lds[64][65];
  const int t = threadIdx.x;
  const int b = blockIdx.z;
  const float* src = attn + (size_t)b * D_ * D_;
  u16* dst = attnT + (size_t)b * D_ * D_;
  const int d0 = blockIdx.x * 64, e0 = blockIdx.y * 64;
#pragma unroll
  for (int i = 0; i < 4; ++i) {
    const int fidx = i * 256 + t;
    const int r = fidx >> 4, c4 = fidx & 15;
    const f32x4 f = *(const f32x4*)(src + (size_t)(d0 + r) * D_ + e0 + c4 * 4);
#pragma unroll
    for (int jj = 0; jj < 4; ++jj) lds[r][c4 * 4 + jj] = f[jj];
  }
  __syncthreads();
#pragma unroll
  for (int j = 0; j < 2; ++j) {
    const int sidx = j * 256 + t;
    const int rd = sidx >> 3, c8 = sidx & 7;
    u16x8 o;
#pragma unroll
    for (int jj = 0; jj < 8; ++jj) o[jj] = f2bf(lds[c8 * 8 + jj][rd]);
    *(u16x8*)(dst + (size_t)(e0 + rd) * D_ + d0 + c8 * 8) = o;
  }
}

// gemm2: out[b][n][e] = sum_d v[b][n][d] * attnT[b][e][d]  (r14-proven, 3D grid)
__global__ __launch_bounds__(256) void k_gemm2(const float* __restrict__ v,
                                               const u16* __restrict__ attnT,
                                               float* __restrict__ out) {
  __shared__ u16 As2[2][128 * 32];
  __shared__ u16 Bs2[2][128 * 32];
  const int bm = blockIdx.x, bn = blockIdx.y, b = blockIdx.z;
  const float* Ab = v + (size_t)b * ((size_t)N_ * D_) + (size_t)(bm * 128) * D_;
  const u16* Bb = attnT + (size_t)b * ((size_t)D_ * D_) + (size_t)(bn * 128) * D_;
  float* C = out + (size_t)b * ((size_t)N_ * D_);
  const int tid = threadIdx.x;
  const int wave = tid >> 6, lane = tid & 63;
  const int wr = wave >> 1, wc = wave & 1;
  const int lrow = lane & 15, lk = (lane >> 4) * 8;
  const int srow = lane >> 2, scol = (lane & 3) * 8;
  const int arow0 = tid >> 2, ac8 = tid & 3;
  f32x4 acc[4][4];
#pragma unroll
  for (int m = 0; m < 4; ++m)
#pragma unroll
    for (int n = 0; n < 4; ++n) acc[m][n] = f32x4{0.f, 0.f, 0.f, 0.f};

  f32x4 rf0[2], rf1[2];
#pragma unroll
  for (int i = 0; i < 2; ++i) {
    const int row = i * 64 + arow0;
    rf0[i] = *(const f32x4*)(Ab + (size_t)row * D_ + ac8 * 8);
    rf1[i] = *(const f32x4*)(Ab + (size_t)row * D_ + ac8 * 8 + 4);
  }

  for (int kt = 0; kt < 16; ++kt) {
    const int k0 = kt * 32;
    u16* Ad = As2[kt & 1];
    u16* Bd = Bs2[kt & 1];
#pragma unroll
    for (int i = 0; i < 2; ++i) {
      const int cc = i * 4 + wave;
      load_lds16(Bb + (size_t)(cc * 16 + srow) * D_ + k0 + scol, Bd + cc * 512);
    }
#pragma unroll
    for (int i = 0; i < 2; ++i) {
      const int row = i * 64 + arow0;
      bf16x8 o;
#pragma unroll
      for (int jj = 0; jj < 4; ++jj) {
        o[jj] = (__bf16)rf0[i][jj];
        o[4 + jj] = (__bf16)rf1[i][jj];
      }
      *(bf16x8*)(Ad + row * 32 + ac8 * 8) = o;
    }
    if (kt + 1 < 16) {
#pragma unroll
      for (int i = 0; i < 2; ++i) {
        const int row = i * 64 + arow0;
        rf0[i] = *(const f32x4*)(Ab + (size_t)row * D_ + (k0 + 32) + ac8 * 8);
        rf1[i] = *(const f32x4*)(Ab + (size_t)row * D_ + (k0 + 32) + ac8 * 8 + 4);
      }
    }
    __syncthreads();
    bf16x8 af[4], bfv[4];
#pragma unroll
    for (int m = 0; m < 4; ++m)
      af[m] = *(const bf16x8*)(Ad + (wr * 64 + m * 16 + lrow) * 32 + lk);
#pragma unroll
    for (int n = 0; n < 4; ++n)
      bfv[n] = *(const bf16x8*)(Bd + (wc * 64 + n * 16 + lrow) * 32 + lk);
#pragma unroll
    for (int m = 0; m < 4; ++m)
#pragma unroll
      for (int n = 0; n < 4; ++n)
        acc[m][n] = __builtin_amdgcn_mfma_f32_16x16x32_bf16(af[m], bfv[n],
                                                            acc[m][n], 0, 0, 0);
  }
  const int crow = (lane >> 4) * 4, ccol = lane & 15;
#pragma unroll
  for (int m = 0; m < 4; ++m) {
    const int grow = bm * 128 + wr * 64 + m * 16 + crow;
#pragma unroll
    for (int n = 0; n < 4; ++n) {
      const int gcol = bn * 128 + wc * 64 + n * 16 + ccol;
#pragma unroll
      for (int i2 = 0; i2 < 4; ++i2)
        C[(size_t)(grow + i2) * D_ + gcol] = acc[m][n][i2];
    }
  }
}

extern "C" void kernel_launch(void* const* d_in, const int* in_sizes, int n_in,
                              void* d_out, int out_size, void* d_ws, size_t ws_size,
                              hipStream_t stream) {
  const float* v = (const float*)d_in[0];
  const float* k = (const float*)d_in[1];
  float* out = (float*)d_out;
  float* attn = out + (size_t)B_ * N_ * D_;
  float* Sp = (float*)d_out;  // 8 x 8 MiB partials in the (dead) out region
  u16* attnT = (u16*)d_ws;    // 4 MiB

  k_gemm1d<<<dim3(256), dim3(512), 0, stream>>>(k, v, Sp);
  k_softmax<<<dim3(1024), dim3(256), 0, stream>>>(Sp, attn);
  k_attn_t<<<dim3(8, 8, 8), dim3(256), 0, stream>>>(attn, attnT);
  k_gemm2<<<dim3(32, 4, 8), dim3(256), 0, stream>>>(v, attnT, out);
}